// Round 1
// baseline (7941.201 us; speedup 1.0000x reference)
//
#include <hip/hip_runtime.h>
#include <math.h>

#define Bsz  8192
#define Mdim 512
#define Ndim 2048
#define Kit  16
#define Pk   50
#define EPSv 0.01f

// ---------------------------------------------------------------------------
// b = -y  (iteration 0: x == 0  =>  (gain*x)@A^T - y = -y)
// ---------------------------------------------------------------------------
__global__ __launch_bounds__(256) void negy_kernel(const float* __restrict__ y,
                                                   float* __restrict__ b) {
    int i = blockIdx.x * 256 + threadIdx.x;           // float4 index
    float4 v = ((const float4*)y)[i];
    float4 o = { -v.x, -v.y, -v.z, -v.w };
    ((float4*)b)[i] = o;
}

// ---------------------------------------------------------------------------
// GEMM1 (NT): b[B,M] = z @ A^T - y      z:(B,N) rowmajor, A:(M,N) rowmajor
// tile 128(rows) x 64(cols), BK=32, 256 thr, micro 8x4
// ---------------------------------------------------------------------------
__global__ __launch_bounds__(256) void gemm1_kernel(const float* __restrict__ z,
                                                    const float* __restrict__ A,
                                                    const float* __restrict__ y,
                                                    float* __restrict__ b) {
    const int tid = threadIdx.x;
    const int tx  = tid & 15;          // 16 col-groups * 4 cols
    const int ty  = tid >> 4;          // 16 row-groups * 8 rows
    const int m0  = blockIdx.x * 64;
    const int r0  = blockIdx.y * 128;

    __shared__ float zt[32][132];      // [k][row], pad 4 keeps 16B align
    __shared__ float at[32][68];       // [k][m]

    float acc[8][4];
#pragma unroll
    for (int i = 0; i < 8; i++)
#pragma unroll
        for (int j = 0; j < 4; j++) acc[i][j] = 0.f;

    for (int k0 = 0; k0 < Ndim; k0 += 32) {
        // stage z: 128 rows x 32 k = 1024 float4
#pragma unroll
        for (int s = 0; s < 4; ++s) {
            int f   = tid + s * 256;
            int row = f >> 3;
            int kk  = (f & 7) << 2;
            float4 v = *(const float4*)(z + (size_t)(r0 + row) * Ndim + k0 + kk);
            zt[kk + 0][row] = v.x; zt[kk + 1][row] = v.y;
            zt[kk + 2][row] = v.z; zt[kk + 3][row] = v.w;
        }
        // stage A: 64 m x 32 k = 512 float4
#pragma unroll
        for (int s = 0; s < 2; ++s) {
            int f  = tid + s * 256;
            int m  = f >> 3;
            int kk = (f & 7) << 2;
            float4 v = *(const float4*)(A + (size_t)(m0 + m) * Ndim + k0 + kk);
            at[kk + 0][m] = v.x; at[kk + 1][m] = v.y;
            at[kk + 2][m] = v.z; at[kk + 3][m] = v.w;
        }
        __syncthreads();
#pragma unroll
        for (int k = 0; k < 32; ++k) {
            float4 z0 = *(const float4*)&zt[k][ty * 8];
            float4 z1 = *(const float4*)&zt[k][ty * 8 + 4];
            float4 a0 = *(const float4*)&at[k][tx * 4];
            float zr[8] = { z0.x, z0.y, z0.z, z0.w, z1.x, z1.y, z1.z, z1.w };
            float ar[4] = { a0.x, a0.y, a0.z, a0.w };
#pragma unroll
            for (int i = 0; i < 8; i++)
#pragma unroll
                for (int j = 0; j < 4; j++)
                    acc[i][j] = fmaf(zr[i], ar[j], acc[i][j]);
        }
        __syncthreads();
    }
#pragma unroll
    for (int i = 0; i < 8; i++) {
        int row = r0 + ty * 8 + i;
        float4 yv = *(const float4*)(y + (size_t)row * Mdim + m0 + tx * 4);
        float4 o;
        o.x = acc[i][0] - yv.x; o.y = acc[i][1] - yv.y;
        o.z = acc[i][2] - yv.z; o.w = acc[i][3] - yv.w;
        *(float4*)(b + (size_t)row * Mdim + m0 + tx * 4) = o;
    }
}

// ---------------------------------------------------------------------------
// GEMM2 (NN): u[B,N] = x - gamma * (b @ A)    b:(B,M), A:(M,N), x:(B,N)
// tile 128x128, BK=16, 256 thr, micro 8x8
// ---------------------------------------------------------------------------
__global__ __launch_bounds__(256) void gemm2_kernel(const float* __restrict__ bmat,
                                                    const float* __restrict__ A,
                                                    const float* __restrict__ x,
                                                    const float* __restrict__ gamma,
                                                    int it,
                                                    float* __restrict__ u) {
    const int tid = threadIdx.x;
    const int tx  = tid & 15;
    const int ty  = tid >> 4;
    const int n0  = blockIdx.x * 128;
    const int r0  = blockIdx.y * 128;
    const float g = gamma[it];

    __shared__ float bt[16][132];      // [k][row]
    __shared__ float at[16][132];      // [k][n]

    float acc[8][8];
#pragma unroll
    for (int i = 0; i < 8; i++)
#pragma unroll
        for (int j = 0; j < 8; j++) acc[i][j] = 0.f;

    for (int k0 = 0; k0 < Mdim; k0 += 16) {
        // stage b: 128 rows x 16 k = 512 float4 (transpose to [k][row])
#pragma unroll
        for (int s = 0; s < 2; ++s) {
            int f   = tid + s * 256;
            int row = f >> 2;
            int kk  = (f & 3) << 2;
            float4 v = *(const float4*)(bmat + (size_t)(r0 + row) * Mdim + k0 + kk);
            bt[kk + 0][row] = v.x; bt[kk + 1][row] = v.y;
            bt[kk + 2][row] = v.z; bt[kk + 3][row] = v.w;
        }
        // stage A: 16 k x 128 n = 512 float4 (direct, coalesced)
#pragma unroll
        for (int s = 0; s < 2; ++s) {
            int f  = tid + s * 256;
            int m  = f >> 5;
            int nn = (f & 31) << 2;
            *(float4*)&at[m][nn] =
                *(const float4*)(A + (size_t)(k0 + m) * Ndim + n0 + nn);
        }
        __syncthreads();
#pragma unroll
        for (int k = 0; k < 16; ++k) {
            float4 b0 = *(const float4*)&bt[k][ty * 8];
            float4 b1 = *(const float4*)&bt[k][ty * 8 + 4];
            float4 a0 = *(const float4*)&at[k][tx * 8];
            float4 a1 = *(const float4*)&at[k][tx * 8 + 4];
            float br[8] = { b0.x, b0.y, b0.z, b0.w, b1.x, b1.y, b1.z, b1.w };
            float ar[8] = { a0.x, a0.y, a0.z, a0.w, a1.x, a1.y, a1.z, a1.w };
#pragma unroll
            for (int i = 0; i < 8; i++)
#pragma unroll
                for (int j = 0; j < 8; j++)
                    acc[i][j] = fmaf(br[i], ar[j], acc[i][j]);
        }
        __syncthreads();
    }
#pragma unroll
    for (int i = 0; i < 8; i++) {
        int row = r0 + ty * 8 + i;
#pragma unroll
        for (int jj = 0; jj < 2; jj++) {
            int col   = n0 + tx * 8 + jj * 4;
            float4 xv = *(const float4*)(x + (size_t)row * Ndim + col);
            float4 o;
            o.x = xv.x - g * acc[i][jj * 4 + 0];
            o.y = xv.y - g * acc[i][jj * 4 + 1];
            o.z = xv.z - g * acc[i][jj * 4 + 2];
            o.w = xv.w - g * acc[i][jj * 4 + 3];
            *(float4*)(u + (size_t)row * Ndim + col) = o;
        }
    }
}

// ---------------------------------------------------------------------------
// Fused per-row: exact 50th-largest |u| via 4-pass radix select, then
// soft-threshold + overshoot update of x, then z = gain_{it+1} * x_new.
// One block (256 thr) per row; u and z share the same buffer (read-before-
// write per element, all u values held in registers before any store).
// ---------------------------------------------------------------------------
__global__ __launch_bounds__(256) void topk_update_kernel(
    float* __restrict__ uz, float* __restrict__ x,
    const float* __restrict__ theta, const float* __restrict__ a_param,
    const float* __restrict__ vv, const float* __restrict__ vu, int it) {
    const int row = blockIdx.x;
    const int t   = threadIdx.x;
    float* urow = uz + (size_t)row * Ndim;
    float* xrow = x  + (size_t)row * Ndim;

    float4 u0 = *(const float4*)(urow + 4 * t);
    float4 u1 = *(const float4*)(urow + 4 * t + 1024);
    float uvals[8] = { u0.x, u0.y, u0.z, u0.w, u1.x, u1.y, u1.z, u1.w };
    unsigned keys[8];
#pragma unroll
    for (int e = 0; e < 8; e++) keys[e] = __float_as_uint(fabsf(uvals[e]));

    __shared__ unsigned bins[256];
    __shared__ unsigned scan[256];
    __shared__ unsigned sel[2];

    unsigned prefix = 0;
    int k = Pk;
#pragma unroll
    for (int pass = 0; pass < 4; ++pass) {
        int shift = 24 - pass * 8;
        bins[t] = 0;
        __syncthreads();
        unsigned himask = (pass == 0) ? 0u : (0xFFFFFFFFu << (shift + 8));
#pragma unroll
        for (int e = 0; e < 8; e++) {
            if ((keys[e] & himask) == prefix)
                atomicAdd(&bins[(keys[e] >> shift) & 255], 1u);
        }
        __syncthreads();
        unsigned val = bins[t];
        scan[t] = val;
        __syncthreads();
        // inclusive suffix sum over 256 bins
        for (int off = 1; off < 256; off <<= 1) {
            unsigned add = (t + off < 256) ? scan[t + off] : 0u;
            __syncthreads();
            scan[t] += add;
            __syncthreads();
        }
        unsigned suf   = scan[t];
        unsigned above = suf - val;
        if (suf >= (unsigned)k && above < (unsigned)k) {
            sel[0] = (unsigned)t;
            sel[1] = (unsigned)k - above;
        }
        __syncthreads();
        prefix |= sel[0] << shift;
        k = (int)sel[1];
        __syncthreads();
    }
    const float thresh = __uint_as_float(prefix);   // exact 50th-largest |u|

    const float th = theta[it];
    const float ap = a_param[it];
    const bool haveNext = (it + 1) < Kit;
    float tn = 0.f, vn = 0.f, vun = 0.f;
    if (haveNext) { tn = theta[it + 1]; vn = vv[it + 1]; vun = vu[it + 1]; }

    float4 x0 = *(const float4*)(xrow + 4 * t);
    float4 x1 = *(const float4*)(xrow + 4 * t + 1024);
    float xv[8] = { x0.x, x0.y, x0.z, x0.w, x1.x, x1.y, x1.z, x1.w };

    float xo[8], zo[8];
#pragma unroll
    for (int e = 0; e < 8; e++) {
        float uval = uvals[e];
        float au   = fabsf(uval);
        bool keep  = au > thresh;                      // strict, matches jax
        float shr  = copysignf(fmaxf(au - th, 0.f), uval);
        float xn   = keep ? uval : shr;
        float d    = xn - xv[e];
        float ov   = 1.f + ap / (fabsf(d) + EPSv);
        float xr   = xv[e] + ov * d;
        xo[e] = xr;
        zo[e] = (1.f + tn * vun * __expf(-vn * fabsf(xr))) * xr;
    }
    float4 a0 = { xo[0], xo[1], xo[2], xo[3] };
    float4 a1 = { xo[4], xo[5], xo[6], xo[7] };
    *(float4*)(xrow + 4 * t) = a0;
    *(float4*)(xrow + 4 * t + 1024) = a1;
    if (haveNext) {
        float4 z0 = { zo[0], zo[1], zo[2], zo[3] };
        float4 z1 = { zo[4], zo[5], zo[6], zo[7] };
        *(float4*)(urow + 4 * t) = z0;
        *(float4*)(urow + 4 * t + 1024) = z1;
    }
}

// ---------------------------------------------------------------------------
extern "C" void kernel_launch(void* const* d_in, const int* in_sizes, int n_in,
                              void* d_out, int out_size, void* d_ws, size_t ws_size,
                              hipStream_t stream) {
    const float* y       = (const float*)d_in[0];   // (B,M)
    const float* A       = (const float*)d_in[1];   // (M,N)
    const float* gamma   = (const float*)d_in[2];   // (K)
    const float* theta   = (const float*)d_in[3];   // (K)
    const float* a_param = (const float*)d_in[4];   // (K)
    const float* v       = (const float*)d_in[5];   // (K)
    const float* vu      = (const float*)d_in[6];   // (K)
    // d_in[7] = theta_init (only multiplies x==0 at iter 0 -> unused)
    // d_in[8] = info (unused)

    float* x  = (float*)d_out;                      // (B,N), tail 2K zeros
    float* uz = (float*)d_ws;                       // (B,N)  u / z shared
    float* bm = uz + (size_t)Bsz * Ndim;            // (B,M)

    // zero x and the two (K,1) zero outputs; poisoned 0xAA otherwise
    hipMemsetAsync(d_out, 0, (size_t)out_size * sizeof(float), stream);

    dim3 blk(256);
    dim3 g1(Mdim / 64, Bsz / 128);
    dim3 g2(Ndim / 128, Bsz / 128);

    for (int it = 0; it < Kit; ++it) {
        if (it == 0) {
            negy_kernel<<<(Bsz * Mdim / 4) / 256, blk, 0, stream>>>(y, bm);
        } else {
            gemm1_kernel<<<g1, blk, 0, stream>>>(uz, A, y, bm);
        }
        gemm2_kernel<<<g2, blk, 0, stream>>>(bm, A, x, gamma, it, uz);
        topk_update_kernel<<<Bsz, blk, 0, stream>>>(uz, x, theta, a_param, v, vu, it);
    }
}